// Round 1
// baseline (234.994 us; speedup 1.0000x reference)
//
#include <hip/hip_runtime.h>
#include <hip/hip_bf16.h>

#define BB 64
#define TT 4096
#define DD 128
#define KK 512

// ---------------------------------------------------------------------------
// Kernel 1: scores[b*T+t] = dot(emb[b,t,:], W) + b0 ; masked -> -inf
// One wave (64 lanes) per token: lane l holds emb[t, 2l:2l+2] and W[2l:2l+2].
// Double accumulation so our scores are exact (top-k boundary robustness vs
// the fp32 numpy reference).
// ---------------------------------------------------------------------------
__global__ __launch_bounds__(256) void k_scores(
    const float* __restrict__ emb, const int* __restrict__ mask,
    const float* __restrict__ W, const float* __restrict__ bias,
    float* __restrict__ scores)
{
    const int wave = threadIdx.x >> 6;
    const int lane = threadIdx.x & 63;
    const int token0 = (blockIdx.x * 4 + wave) * 16;   // 16 tokens per wave

    const float2 w = ((const float2*)W)[lane];
    const double wx = (double)w.x, wy = (double)w.y;
    const double b0 = (double)bias[0];

    for (int i = 0; i < 16; ++i) {
        const int t = token0 + i;                      // global token in [0, B*T)
        const float2 e = ((const float2*)emb)[(size_t)t * 64 + lane];
        double s = (double)e.x * wx + (double)e.y * wy;
        s += __shfl_xor(s, 32, 64);
        s += __shfl_xor(s, 16, 64);
        s += __shfl_xor(s,  8, 64);
        s += __shfl_xor(s,  4, 64);
        s += __shfl_xor(s,  2, 64);
        s += __shfl_xor(s,  1, 64);
        if (lane == 0) {
            const float val = (float)(s + b0);
            scores[t] = mask[t] ? val : __uint_as_float(0xFF800000u); // -inf
        }
    }
}

// ---------------------------------------------------------------------------
// Kernel 2: per-row exact top-K selection (ties -> lower index), emitting
// selected token indices in ASCENDING token order (== sorted topk_idx) plus
// the gathered mask as 0/1 floats.
// One block (256 threads) per batch row. Keys are monotone uint32 transforms
// of the fp32 scores. 4-pass MSB radix select finds the exact Kth key.
// ---------------------------------------------------------------------------
__global__ __launch_bounds__(256) void k_select(
    const float* __restrict__ scores, const int* __restrict__ mask,
    int* __restrict__ idx_out, float* __restrict__ mask_out)
{
    __shared__ unsigned int keys[TT];      // 16 KB
    __shared__ unsigned int hist[256];
    __shared__ unsigned int scanbuf[256];
    __shared__ unsigned int bcast[2];      // [0]=chosen bin, [1]=new count_above

    const int row = blockIdx.x;
    const int tid = threadIdx.x;
    const float* srow = scores + (size_t)row * TT;
    const int*   mrow = mask   + (size_t)row * TT;

    // Load + monotone key transform. Thread tid owns tokens [tid*16, tid*16+16).
    for (int i = 0; i < 16; ++i) {
        const int t = tid * 16 + i;
        const unsigned int u = __float_as_uint(srow[t]);
        keys[t] = (u & 0x80000000u) ? ~u : (u | 0x80000000u);
    }
    __syncthreads();

    // ---- radix select: find key of the Kth largest element ----
    unsigned int prefix = 0;        // high bytes decided so far
    unsigned int count_above = 0;   // #keys strictly greater than current prefix range
    for (int pass = 0; pass < 4; ++pass) {
        const int shift = 24 - 8 * pass;
        hist[tid] = 0;
        __syncthreads();
        for (int i = 0; i < 16; ++i) {
            const unsigned int k = keys[tid * 16 + i];
            const bool in_group = (pass == 0) || ((k >> (shift + 8)) == prefix);
            if (in_group) atomicAdd(&hist[(k >> shift) & 0xFFu], 1u);
        }
        __syncthreads();
        const unsigned int histv = hist[tid];
        // inclusive suffix sum over bins (Hillis-Steele)
        unsigned int v = histv;
        scanbuf[tid] = v;
        __syncthreads();
        for (int off = 1; off < 256; off <<= 1) {
            const unsigned int add = (tid + off < 256) ? scanbuf[tid + off] : 0u;
            __syncthreads();
            v += add;
            scanbuf[tid] = v;
            __syncthreads();
        }
        const unsigned int excl = v - histv;   // #keys in group with byte > tid
        if (count_above + v >= KK && count_above + excl < KK) {
            bcast[0] = (unsigned int)tid;
            bcast[1] = count_above + excl;
        }
        __syncthreads();
        prefix = (prefix << 8) | bcast[0];
        count_above = bcast[1];
        __syncthreads();
    }
    const unsigned int vstar = prefix;            // exact key of Kth largest
    const unsigned int need  = KK - count_above;  // #ties (==vstar) to take, lowest index first

    // ---- emit selected indices in ascending token order ----
    unsigned int gt = 0, eq = 0;
    for (int i = 0; i < 16; ++i) {
        const unsigned int k = keys[tid * 16 + i];
        gt += (k > vstar);
        eq += (k == vstar);
    }
    const unsigned int packed = (gt << 16) | eq;  // counts <= 4096, no overflow
    scanbuf[tid] = packed;
    __syncthreads();
    unsigned int v2 = packed;
    for (int off = 1; off < 256; off <<= 1) {
        const unsigned int add = (tid >= off) ? scanbuf[tid - off] : 0u;
        __syncthreads();
        v2 += add;
        scanbuf[tid] = v2;
        __syncthreads();
    }
    const unsigned int before = v2 - packed;      // exclusive prefix
    unsigned int gt_b = before >> 16;
    unsigned int eq_b = before & 0xFFFFu;
    for (int i = 0; i < 16; ++i) {
        const int t = tid * 16 + i;
        const unsigned int k = keys[t];
        if (k > vstar) {
            const unsigned int pos = gt_b + (eq_b < need ? eq_b : need);
            idx_out[row * KK + pos]  = t;
            mask_out[row * KK + pos] = mrow[t] ? 1.0f : 0.0f;
            gt_b++;
        } else if (k == vstar) {
            if (eq_b < need) {
                const unsigned int pos = gt_b + eq_b;
                idx_out[row * KK + pos]  = t;
                mask_out[row * KK + pos] = mrow[t] ? 1.0f : 0.0f;
            }
            eq_b++;
        }
    }
}

// ---------------------------------------------------------------------------
// Kernel 3: out[b,j,:] = emb[b, idx[b*K+j], :]
// 32 lanes x float4 = 128 floats per selected row; 8 rows per 256-thread block.
// ---------------------------------------------------------------------------
__global__ __launch_bounds__(256) void k_gather(
    const float* __restrict__ emb, const int* __restrict__ idx,
    float* __restrict__ out)
{
    const int gp   = blockIdx.x * 8 + (threadIdx.x >> 5);  // pair index in [0, B*K)
    const int lane = threadIdx.x & 31;
    const int b = gp >> 9;                                  // / KK
    const int t = idx[gp];
    const float4* src = (const float4*)(emb + ((size_t)b * TT + t) * DD);
    float4*       dst = (float4*)(out + (size_t)gp * DD);
    dst[lane] = src[lane];
}

extern "C" void kernel_launch(void* const* d_in, const int* in_sizes, int n_in,
                              void* d_out, int out_size, void* d_ws, size_t ws_size,
                              hipStream_t stream)
{
    const float* emb  = (const float*)d_in[0];   // (B,T,D) fp32
    const int*   mask = (const int*)d_in[1];     // (B,T) bool -> int32 0/1
    // d_in[2] = k (int scalar) -- fixed at 512 for this problem instance
    const float* W    = (const float*)d_in[3];   // (D,)
    const float* bias = (const float*)d_in[4];   // (1,)

    float* out_sel  = (float*)d_out;                        // B*K*D floats
    float* out_mask = (float*)d_out + (size_t)BB * KK * DD; // B*K floats

    float* scores = (float*)d_ws;                                        // B*T floats (1 MB)
    int*   idx    = (int*)((char*)d_ws + (size_t)BB * TT * sizeof(float)); // B*K ints

    k_scores<<<BB * TT / 64, 256, 0, stream>>>(emb, mask, W, bias, scores);
    k_select<<<BB, 256, 0, stream>>>(scores, mask, idx, out_mask);
    k_gather<<<BB * KK / 8, 256, 0, stream>>>(emb, idx, out_sel);
}

// Round 2
// 219.699 us; speedup vs baseline: 1.0696x; 1.0696x over previous
//
#include <hip/hip_runtime.h>
#include <hip/hip_bf16.h>

#define BB 64
#define TT 4096
#define DD 128
#define KK 512

// ---------------------------------------------------------------------------
// Kernel 1: scores[b*T+t] = dot(emb[b,t,:], W) + b0 ; masked -> -inf
// Each 64-lane wave processes 2 tokens per iteration: lanes 0-31 -> token 2p,
// lanes 32-63 -> token 2p+1. Each lane loads float4 (16B, perfectly
// coalesced: wave covers 2 contiguous 512B rows). Reduction is 5 shfl_xor
// levels with offsets 16..1 (all intra-32 -> DPP/swizzle, no ds_permute).
// Double accumulation keeps our scores exact vs the np reference top-k.
// ---------------------------------------------------------------------------
__global__ __launch_bounds__(256) void k_scores(
    const float* __restrict__ emb, const int* __restrict__ mask,
    const float* __restrict__ W, const float* __restrict__ bias,
    float* __restrict__ scores)
{
    const int wave = threadIdx.x >> 6;
    const int lane = threadIdx.x & 63;
    const int half = lane >> 5;        // which token of the pair
    const int sub  = lane & 31;        // dim quarter within token
    // 8 iterations x 2 tokens = 16 tokens per wave; 64 tokens per block
    const int pair0 = (blockIdx.x * 4 + wave) * 8;

    const float4 w = ((const float4*)W)[sub];
    const double w0 = (double)w.x, w1 = (double)w.y, w2 = (double)w.z, w3 = (double)w.w;
    const double b0 = (double)bias[0];

#pragma unroll
    for (int i = 0; i < 8; ++i) {
        const int t = (pair0 + i) * 2 + half;          // global token in [0, B*T)
        const float4 e = ((const float4*)emb)[(size_t)t * 32 + sub];
        double s = (double)e.x * w0 + (double)e.y * w1
                 + (double)e.z * w2 + (double)e.w * w3;
        s += __shfl_xor(s, 16, 64);
        s += __shfl_xor(s,  8, 64);
        s += __shfl_xor(s,  4, 64);
        s += __shfl_xor(s,  2, 64);
        s += __shfl_xor(s,  1, 64);
        if (sub == 0) {
            const float val = (float)(s + b0);
            scores[t] = mask[t] ? val : __uint_as_float(0xFF800000u); // -inf
        }
    }
}

// ---------------------------------------------------------------------------
// Block-wide (256 threads) inclusive prefix sum in tid order using wave
// shuffle scans + 4-element cross-wave combine. 2 barriers total.
// ---------------------------------------------------------------------------
__device__ __forceinline__ unsigned int block_incl_prefix(
    unsigned int v, int tid, volatile unsigned int* wsum)
{
    const int lane = tid & 63, wv = tid >> 6;
#pragma unroll
    for (int off = 1; off < 64; off <<= 1) {
        const unsigned int u = __shfl_up(v, off, 64);
        if (lane >= off) v += u;
    }
    if (lane == 63) wsum[wv] = v;
    __syncthreads();
    unsigned int add = 0;
    for (int w = 0; w < wv; ++w) add += wsum[w];
    v += add;
    __syncthreads();   // protect wsum for reuse
    return v;
}

// ---------------------------------------------------------------------------
// Kernel 2: per-row exact top-K (ties -> lower index), emitting selected
// token indices in ASCENDING token order + gathered mask as 0/1 floats.
// One 256-thread block per batch row; 4-pass MSB radix select over monotone
// uint keys in LDS. All scans are wave-shuffle based (few barriers).
// ---------------------------------------------------------------------------
__global__ __launch_bounds__(256) void k_select(
    const float* __restrict__ scores, const int* __restrict__ mask,
    int* __restrict__ idx_out, float* __restrict__ mask_out)
{
    __shared__ unsigned int keys[TT];        // 16 KB
    __shared__ unsigned int hist4[4][256];   // 4 KB, per-wave histograms
    __shared__ unsigned int wsum[4];
    __shared__ unsigned int bcast[2];        // [0]=chosen bin, [1]=new count_above

    const int row = blockIdx.x;
    const int tid = threadIdx.x;
    const int wv  = tid >> 6;
    const float* srow = scores + (size_t)row * TT;
    const int*   mrow = mask   + (size_t)row * TT;

    // Load + monotone key transform. Thread tid owns tokens [tid*16, tid*16+16).
#pragma unroll
    for (int i = 0; i < 16; ++i) {
        const int t = tid * 16 + i;
        const unsigned int u = __float_as_uint(srow[t]);
        keys[t] = (u & 0x80000000u) ? ~u : (u | 0x80000000u);
    }

    // ---- radix select: find key of the Kth largest element ----
    unsigned int prefix = 0;        // high bytes decided so far
    unsigned int count_above = 0;   // #keys strictly greater than current range
    for (int pass = 0; pass < 4; ++pass) {
        const int shift = 24 - 8 * pass;
#pragma unroll
        for (int w = 0; w < 4; ++w) hist4[w][tid] = 0;
        __syncthreads();
#pragma unroll
        for (int i = 0; i < 16; ++i) {
            const unsigned int k = keys[tid * 16 + i];
            const bool in_group = (pass == 0) || ((k >> (shift + 8)) == prefix);
            if (in_group) atomicAdd(&hist4[wv][(k >> shift) & 0xFFu], 1u);
        }
        __syncthreads();
        // Suffix-sum over bins: thread tid processes bin (255 - tid) so an
        // ascending-tid prefix scan gives descending-bin (suffix) sums.
        const unsigned int bin = 255u - (unsigned int)tid;
        const unsigned int h = hist4[0][bin] + hist4[1][bin]
                             + hist4[2][bin] + hist4[3][bin];
        const unsigned int incl = block_incl_prefix(h, tid, wsum); // #keys with byte >= bin
        const unsigned int excl = incl - h;                        // #keys with byte >  bin
        if (count_above + incl >= KK && count_above + excl < KK) {
            bcast[0] = bin;
            bcast[1] = count_above + excl;
        }
        __syncthreads();
        prefix = (prefix << 8) | bcast[0];
        count_above = bcast[1];
        __syncthreads();
    }
    const unsigned int vstar = prefix;            // exact key of Kth largest
    const unsigned int need  = KK - count_above;  // #ties to take, lowest index first

    // ---- emit selected indices in ascending token order ----
    unsigned int gt = 0, eq = 0;
#pragma unroll
    for (int i = 0; i < 16; ++i) {
        const unsigned int k = keys[tid * 16 + i];
        gt += (k > vstar);
        eq += (k == vstar);
    }
    const unsigned int packed = (gt << 16) | eq;  // counts <= 4096, no overflow
    const unsigned int incl2 = block_incl_prefix(packed, tid, wsum);
    const unsigned int before = incl2 - packed;   // exclusive prefix
    unsigned int gt_b = before >> 16;
    unsigned int eq_b = before & 0xFFFFu;
#pragma unroll
    for (int i = 0; i < 16; ++i) {
        const int t = tid * 16 + i;
        const unsigned int k = keys[t];
        if (k > vstar) {
            const unsigned int pos = gt_b + (eq_b < need ? eq_b : need);
            idx_out[row * KK + pos]  = t;
            mask_out[row * KK + pos] = mrow[t] ? 1.0f : 0.0f;
            gt_b++;
        } else if (k == vstar) {
            if (eq_b < need) {
                const unsigned int pos = gt_b + eq_b;
                idx_out[row * KK + pos]  = t;
                mask_out[row * KK + pos] = mrow[t] ? 1.0f : 0.0f;
            }
            eq_b++;
        }
    }
}

// ---------------------------------------------------------------------------
// Kernel 3: out[b,j,:] = emb[b, idx[b*K+j], :]
// 32 lanes x float4 = 128 floats per selected row; 8 rows per 256-thread block.
// ---------------------------------------------------------------------------
__global__ __launch_bounds__(256) void k_gather(
    const float* __restrict__ emb, const int* __restrict__ idx,
    float* __restrict__ out)
{
    const int gp   = blockIdx.x * 8 + (threadIdx.x >> 5);  // selected-row index in [0, B*K)
    const int lane = threadIdx.x & 31;
    const int b = gp >> 9;                                  // / KK
    const int t = idx[gp];
    const float4* src = (const float4*)(emb + ((size_t)b * TT + t) * DD);
    float4*       dst = (float4*)(out + (size_t)gp * DD);
    dst[lane] = src[lane];
}

extern "C" void kernel_launch(void* const* d_in, const int* in_sizes, int n_in,
                              void* d_out, int out_size, void* d_ws, size_t ws_size,
                              hipStream_t stream)
{
    const float* emb  = (const float*)d_in[0];   // (B,T,D) fp32
    const int*   mask = (const int*)d_in[1];     // (B,T) bool -> int32 0/1
    // d_in[2] = k (int scalar) -- fixed at 512 for this problem instance
    const float* W    = (const float*)d_in[3];   // (D,)
    const float* bias = (const float*)d_in[4];   // (1,)

    float* out_sel  = (float*)d_out;                        // B*K*D floats
    float* out_mask = (float*)d_out + (size_t)BB * KK * DD; // B*K floats

    float* scores = (float*)d_ws;                                          // B*T floats (1 MB)
    int*   idx    = (int*)((char*)d_ws + (size_t)BB * TT * sizeof(float)); // B*K ints

    k_scores<<<BB * TT / 64, 256, 0, stream>>>(emb, mask, W, bias, scores);
    k_select<<<BB, 256, 0, stream>>>(scores, mask, idx, out_mask);
    k_gather<<<BB * KK / 8, 256, 0, stream>>>(emb, idx, out_sel);
}

// Round 3
// 212.872 us; speedup vs baseline: 1.1039x; 1.0321x over previous
//
#include <hip/hip_runtime.h>
#include <hip/hip_bf16.h>

#define BB 64
#define TT 4096
#define DD 128
#define KK 512

// key(-inf): bits(-inf)=0xFF800000, sign set -> ~u = 0x007FFFFF.
// All finite score keys are >= 0x00800000, so masked tokens sort strictly last.
#define KEY_NEG_INF 0x007FFFFFu

// ---------------------------------------------------------------------------
// Kernel 1: keys[b*T+t] = monotone_uint( dot(emb[b,t,:], W) + b0 ), masked -> key(-inf)
// Each 64-lane wave: 2 tokens/iter (half-wave each), float4 loads (16B/lane,
// wave covers 2 contiguous 512B rows -> perfect coalescing). 5 intra-32
// shfl_xor levels. Double accumulation keeps the top-k set exact vs the fp32
// numpy reference (absmax 0.0 in R1/R2).
// ---------------------------------------------------------------------------
__global__ __launch_bounds__(256) void k_scores(
    const float* __restrict__ emb, const int* __restrict__ mask,
    const float* __restrict__ W, const float* __restrict__ bias,
    unsigned int* __restrict__ keys_out)
{
    const int wave = threadIdx.x >> 6;
    const int lane = threadIdx.x & 63;
    const int half = lane >> 5;        // which token of the pair
    const int sub  = lane & 31;        // dim quarter within token
    const int pair0 = (blockIdx.x * 4 + wave) * 8;   // 16 tokens per wave

    const float4 w = ((const float4*)W)[sub];
    const double w0 = (double)w.x, w1 = (double)w.y, w2 = (double)w.z, w3 = (double)w.w;
    const double b0 = (double)bias[0];

#pragma unroll
    for (int i = 0; i < 8; ++i) {
        const int t = (pair0 + i) * 2 + half;          // global token in [0, B*T)
        const float4 e = ((const float4*)emb)[(size_t)t * 32 + sub];
        double s = (double)e.x * w0 + (double)e.y * w1
                 + (double)e.z * w2 + (double)e.w * w3;
        s += __shfl_xor(s, 16, 64);
        s += __shfl_xor(s,  8, 64);
        s += __shfl_xor(s,  4, 64);
        s += __shfl_xor(s,  2, 64);
        s += __shfl_xor(s,  1, 64);
        if (sub == 0) {
            const float val = (float)(s + b0);
            const unsigned int u = __float_as_uint(val);
            unsigned int key = (u & 0x80000000u) ? ~u : (u | 0x80000000u);
            if (!mask[t]) key = KEY_NEG_INF;
            keys_out[t] = key;
        }
    }
}

// ---------------------------------------------------------------------------
// Kernel 2: per-row exact top-K (ties -> lower index), emitting selected
// token indices in ASCENDING token order + gathered mask as 0/1 floats.
// One 1024-thread block (16 waves) per row -> 4 waves/SIMD for latency hiding.
// Thread tid owns tokens [4*tid, 4*tid+4). 4-pass MSB radix select; 16-way
// privatized histograms (stride 257 to de-alias banks); 256-bin suffix scan
// done by wave 0 alone in registers (wave-synchronous, no barriers).
// ---------------------------------------------------------------------------
__global__ __launch_bounds__(1024) void k_select(
    const unsigned int* __restrict__ keys_in, const int* __restrict__ mask,
    int* __restrict__ idx_out, float* __restrict__ mask_out)
{
    __shared__ unsigned int keys[TT];           // 16 KB
    __shared__ unsigned int hist[16][257];      // ~16.4 KB, per-wave ways
    __shared__ unsigned int hist_final[256];
    __shared__ unsigned int wsum[16];
    __shared__ unsigned int bcast[2];           // [0]=chosen bin, [1]=new count_above

    const int row  = blockIdx.x;
    const int tid  = threadIdx.x;
    const int wv   = tid >> 6;
    const int lane = tid & 63;
    const unsigned int* krow = keys_in + (size_t)row * TT;
    const int*          mrow = mask    + (size_t)row * TT;

    // Coalesced uint4 load of this thread's 4 keys.
    const uint4 kv = ((const uint4*)krow)[tid];
    ((uint4*)keys)[tid] = kv;

    unsigned int prefix = 0;        // high bytes decided so far
    unsigned int count_above = 0;   // #keys strictly greater than current range
    for (int pass = 0; pass < 4; ++pass) {
        const int shift = 24 - 8 * pass;
        for (int i = tid; i < 16 * 257; i += 1024) ((unsigned int*)hist)[i] = 0;
        __syncthreads();
#pragma unroll
        for (int i = 0; i < 4; ++i) {
            const unsigned int k = keys[tid * 4 + i];
            const bool in_group = (pass == 0) || ((k >> (shift + 8)) == prefix);
            if (in_group) atomicAdd(&hist[wv][(k >> shift) & 0xFFu], 1u);
        }
        __syncthreads();
        if (tid < 256) {
            unsigned int s = 0;
#pragma unroll
            for (int w = 0; w < 16; ++w) s += hist[w][tid];
            hist_final[tid] = s;
        }
        __syncthreads();
        if (wv == 0) {
            // Descending-bin order: position p = 4*lane+j handles bin 255-p.
            unsigned int v[4], c[4];
            unsigned int run = 0;
#pragma unroll
            for (int j = 0; j < 4; ++j) {
                v[j] = hist_final[255 - (4 * lane + j)];
                run += v[j];
                c[j] = run;                     // lane-local inclusive
            }
            unsigned int scan = run;
#pragma unroll
            for (int off = 1; off < 64; off <<= 1) {
                const unsigned int u = __shfl_up(scan, off, 64);
                if (lane >= off) scan += u;
            }
            const unsigned int excl_w = scan - run;  // keys in higher bins than this lane's range
#pragma unroll
            for (int j = 0; j < 4; ++j) {
                const unsigned int incl = excl_w + c[j];   // #keys with byte >= bin
                const unsigned int excl = incl - v[j];     // #keys with byte >  bin
                if (count_above + incl >= KK && count_above + excl < KK) {
                    bcast[0] = 255u - (unsigned int)(4 * lane + j);
                    bcast[1] = count_above + excl;
                }
            }
        }
        __syncthreads();
        prefix = (prefix << 8) | bcast[0];
        count_above = bcast[1];
        // No extra barrier: next pass's hist-zero barrier protects bcast reuse.
    }
    const unsigned int vstar = prefix;            // exact key of Kth largest
    const unsigned int need  = KK - count_above;  // #ties to take, lowest index first

    // ---- emit selected indices in ascending token order ----
    unsigned int gt = 0, eq = 0;
#pragma unroll
    for (int i = 0; i < 4; ++i) {
        const unsigned int k = keys[tid * 4 + i];
        gt += (k > vstar);
        eq += (k == vstar);
    }
    unsigned int packed = (gt << 16) | eq;        // counts <= 4096, no overflow
    unsigned int scan = packed;
#pragma unroll
    for (int off = 1; off < 64; off <<= 1) {
        const unsigned int u = __shfl_up(scan, off, 64);
        if (lane >= off) scan += u;
    }
    if (lane == 63) wsum[wv] = scan;
    __syncthreads();
    unsigned int add = 0;
    for (int w = 0; w < wv; ++w) add += wsum[w];  // LDS broadcast reads
    const unsigned int before = scan - packed + add;  // block-exclusive prefix
    unsigned int gt_b = before >> 16;
    unsigned int eq_b = before & 0xFFFFu;
#pragma unroll
    for (int i = 0; i < 4; ++i) {
        const int t = tid * 4 + i;
        const unsigned int k = keys[t];
        if (k > vstar) {
            const unsigned int pos = gt_b + (eq_b < need ? eq_b : need);
            idx_out[row * KK + pos]  = t;
            mask_out[row * KK + pos] = mrow[t] ? 1.0f : 0.0f;
            gt_b++;
        } else if (k == vstar) {
            if (eq_b < need) {
                const unsigned int pos = gt_b + eq_b;
                idx_out[row * KK + pos]  = t;
                mask_out[row * KK + pos] = mrow[t] ? 1.0f : 0.0f;
            }
            eq_b++;
        }
    }
}

// ---------------------------------------------------------------------------
// Kernel 3: out[b,j,:] = emb[b, idx[b*K+j], :]
// 32 lanes x float4 = 128 floats per selected row; 8 rows per 256-thread block.
// ---------------------------------------------------------------------------
__global__ __launch_bounds__(256) void k_gather(
    const float* __restrict__ emb, const int* __restrict__ idx,
    float* __restrict__ out)
{
    const int gp   = blockIdx.x * 8 + (threadIdx.x >> 5);  // selected-row index in [0, B*K)
    const int lane = threadIdx.x & 31;
    const int b = gp >> 9;                                  // / KK
    const int t = idx[gp];
    const float4* src = (const float4*)(emb + ((size_t)b * TT + t) * DD);
    float4*       dst = (float4*)(out + (size_t)gp * DD);
    dst[lane] = src[lane];
}

extern "C" void kernel_launch(void* const* d_in, const int* in_sizes, int n_in,
                              void* d_out, int out_size, void* d_ws, size_t ws_size,
                              hipStream_t stream)
{
    const float* emb  = (const float*)d_in[0];   // (B,T,D) fp32
    const int*   mask = (const int*)d_in[1];     // (B,T) bool -> int32 0/1
    // d_in[2] = k (int scalar) -- fixed at 512 for this problem instance
    const float* W    = (const float*)d_in[3];   // (D,)
    const float* bias = (const float*)d_in[4];   // (1,)

    float* out_sel  = (float*)d_out;                        // B*K*D floats
    float* out_mask = (float*)d_out + (size_t)BB * KK * DD; // B*K floats

    unsigned int* keys = (unsigned int*)d_ws;                                  // B*T uints (1 MB)
    int*          idx  = (int*)((char*)d_ws + (size_t)BB * TT * sizeof(unsigned int)); // B*K ints

    k_scores<<<BB * TT / 64, 256, 0, stream>>>(emb, mask, W, bias, keys);
    k_select<<<BB, 1024, 0, stream>>>(keys, mask, idx, out_mask);
    k_gather<<<BB * KK / 8, 256, 0, stream>>>(emb, idx, out_sel);
}